// Round 22
// baseline (46.098 us; speedup 1.0000x reference)
//
#include <hip/hip_runtime.h>

typedef short short8 __attribute__((ext_vector_type(8)));
typedef float f32x4 __attribute__((ext_vector_type(4)));

#define NN 8
#define CI 64
#define CO 128
#define HH 128
#define WW 128
#define PH 132             // padded (2-halo each side)
#define PW 132
#define MU 0.033333333333333333f

#define WS_W_BYTES (9 * 128 * 64 * 2)        // 147456
#define WS_T_OFF   WS_W_BYTES
#define WS_T_BYTES (NN * PH * PW * 4)        // 557568
#define WS_X_OFF   (WS_T_OFF + WS_T_BYTES)   // 705024
#define WS_X_BYTES ((size_t)NN * PH * PW * CI * 2)   // 17842176
#define WS_NB_OFF  (WS_X_OFF + WS_X_BYTES)   // 18547200
#define WS_TOTAL   (WS_NB_OFF + WS_T_BYTES)  // ~19.1 MB

__device__ __forceinline__ unsigned short f2bf(float f) {
  unsigned u = __float_as_uint(f);
  u += 0x7fffu + ((u >> 16) & 1u);     // round-to-nearest-even
  return (unsigned short)(u >> 16);
}

__device__ __forceinline__ void g2lds16(const void* g, void* l) {
  __builtin_amdgcn_global_load_lds(
      (const __attribute__((address_space(1))) unsigned int*)g,
      (__attribute__((address_space(3))) unsigned int*)l, 16, 0, 0);
}
__device__ __forceinline__ void g2lds4(const void* g, void* l) {
  __builtin_amdgcn_global_load_lds(
      (const __attribute__((address_space(1))) unsigned int*)g,
      (__attribute__((address_space(3))) unsigned int*)l, 4, 0, 0);
}

// ================= FAST PATH =================
// prep: bf16 NHWC padded repack + channel-sum plane T + weights (coalesced
// layout: ws_w[(tap*16 + cb*2 + ks)*64 + lane] short8, lane=hi*16+lo holds
// w[co=cb*16+lo][ic=ks*32+hi*8+j], even taps only). ws_x is PLAIN NHWC
// [n][y][x][ic] bf16 (128 B per pixel; the lx XOR pair cancels).
__global__ __launch_bounds__(256) void prep_kernel(
    const float* __restrict__ in, const float* __restrict__ w,
    unsigned short* __restrict__ ws_w, float* __restrict__ ws_T,
    short8* __restrict__ ws_x) {
  const int b = blockIdx.x, tid = threadIdx.x;
  if (b < 512) {
    __shared__ short8 lx[256][8];            // [px][slot^(px&7)]
    const int n = b >> 6, pair = b & 63;
    const int px = tid;
    const int r = pair * 2 + (px >> 7), x = px & 127;
    const float* src = in + ((size_t)(n * CI) * HH + r) * WW + x;
    float tsum = 0.f;
    #pragma unroll
    for (int g = 0; g < 8; ++g) {
      short8 pk;
      #pragma unroll
      for (int j = 0; j < 8; ++j) {
        const float v = src[(size_t)(g * 8 + j) * (HH * WW)];
        tsum += v;
        pk[j] = (short)f2bf(v);
      }
      lx[px][g ^ (px & 7)] = pk;
    }
    ws_T[(n * PH + r + 2) * PW + (x + 2)] = tsum;
    __syncthreads();
    #pragma unroll
    for (int it = 0; it < 8; ++it) {         // coalesced NHWC store, 16B/lane
      const int G = it * 256 + tid;
      const int px2 = G >> 3, g2 = G & 7;
      const int r2 = pair * 2 + (px2 >> 7), x2 = px2 & 127;
      ws_x[((size_t)(n * PH + r2 + 2) * PW + (x2 + 2)) * 8 + g2] =
          lx[px2][g2 ^ (px2 & 7)];
    }
  } else if (b < 520) {                      // zero the padded borders
    const int n = b - 512;
    const short8 z = {0, 0, 0, 0, 0, 0, 0, 0};
    for (int e = tid; e < 1040 * 8; e += 256) {
      const int px = e >> 3, g = e & 7;
      int y, x;
      if (px < 528) { const int r4 = px / 132; y = (r4 < 2) ? r4 : r4 + 128; x = px - r4 * 132; }
      else { const int q = px - 528; const int c4 = q >> 7; x = (c4 < 2) ? c4 : c4 + 128; y = 2 + (q & 127); }
      ws_x[((size_t)(n * PH + y) * PW + x) * 8 + g] = z;
    }
    for (int e = tid; e < 1040; e += 256) {
      int y, x;
      if (e < 528) { const int r4 = e / 132; y = (r4 < 2) ? r4 : r4 + 128; x = e - r4 * 132; }
      else { const int q = e - 528; const int c4 = q >> 7; x = (c4 < 2) ? c4 : c4 + 128; y = 2 + (q & 127); }
      ws_T[(n * PH + y) * PW + x] = 0.f;
    }
  } else {                                   // weights, coalesced MFMA layout
    const int el = (b - 520) * 256 + tid;    // 0..9215 short8 elements
    const int lane = el & 63;
    const int idx = el >> 6;                 // 0..143 = tap*16 + cb*2 + ks
    const int ks = idx & 1, cb = (idx >> 1) & 7, tap = idx >> 4;
    const int lo = lane & 15, hi = lane >> 4;
    const int ky = (tap / 3) * 2, kx = (tap % 3) * 2;
    const float* wp = w + (size_t)((cb * 16 + lo) * 64 + ks * 32 + hi * 8) * 25
                        + ky * 5 + kx;
    short8 pk;
    #pragma unroll
    for (int j = 0; j < 8; ++j) pk[j] = (short)f2bf(wp[j * 25]);
    ((short8*)ws_w)[el] = pk;
  }
}

// nb: per-pixel neighbor plane, COMPACT [n][128][128] (16B-aligned reads)
__global__ __launch_bounds__(256) void nb_kernel(
    const float* __restrict__ ws_T, float* __restrict__ ws_nb) {
  const int p = blockIdx.x * 256 + threadIdx.x;   // 131072 interior pixels
  const int n = p >> 14, yx = p & 16383;
  const int y = yx >> 7, x = yx & 127;
  const float* Tb = ws_T + (size_t)(n * PH + y) * PW + x;
  float s = 0.f;
  #pragma unroll
  for (int ky = 0; ky < 5; ++ky)
    #pragma unroll
    for (int kx = 0; kx < 5; ++kx)
      if ((ky & 1) | (kx & 1)) s += Tb[ky * PW + kx];
  ws_nb[(size_t)p] = s * MU;
}

// conv v13: v12 (XCD-pinned, 4-row strip, W[36] in regs, 3-deep af pipe) +
// DOUBLE-BUFFERED halo/nb with counted vmcnt: per j the sequence is
//   wait vmcnt(4|0) ; s_barrier ; issue DMA(j+1)->buf^1 ; compute buf ; stores
// so DMA(j+1) overlaps compute(j)+stores(j); stores stay in flight across
// the barrier (never vmcnt(0) in the loop). Per-wave VMEM counts uniform:
// 10 DMA (9 halo + 1 nb-or-dummy) + 4 stores.
__global__ __launch_bounds__(256)
__attribute__((amdgpu_waves_per_eu(2, 2)))
void conv_kernel(
    const unsigned short* __restrict__ ws_w, const float* __restrict__ ws_nb,
    const unsigned short* __restrict__ ws_x, float* __restrict__ out) {
  __shared__ short8 halo[2][288 * 8];  // 2 x 36864 B
  __shared__ float  nbt[2][128];       // 2 x 512 B
  __shared__ float  dmy[128];          // 512 B (vmcnt padding for waves 2,3)

  const int tid = threadIdx.x;
  const int wave = tid >> 6, lane = tid & 63;
  const int bid = blockIdx.x;          // 1024 = (strip*4 + quarter)*8 + n
  const int n = bid & 7;
  const int rest = bid >> 3;
  const int cob = rest & 3;            // co-quarter
  const int ty0 = (rest >> 2) * 4;     // 32 y-strips of 4 rows
  const int lo = lane & 15, hi = lane >> 4;

  // quarter weights -> registers once (36 coalesced b128, L2-hot; static idx)
  const short8* wsv = (const short8*)ws_w;
  short8 W[36];                        // [tap*4 + cbl*2 + ks]
  #pragma unroll
  for (int k = 0; k < 36; ++k)
    W[k] = wsv[((k >> 2) * 16 + cob * 4 + (k & 3)) * 64 + lane];

  // per-unit DMA: exactly 10 wave-instrs (9 halo + 1 nb/dummy)
  auto issue_unit = [&](int tx0, int b) {
    for (int k = wave; k < 36; k += 4) {     // 9 per wave
      const int pos = k * 8 + (lane >> 3);
      const int r = pos / 36, c = pos - r * 36;
      const int chunk = (lane & 7) ^ (pos & 7);
      const unsigned short* g =
          ws_x + ((size_t)(n * PH + ty0 + r) * PW + (tx0 + c)) * 64 + chunk * 8;
      g2lds16(g, (char*)halo[b] + k * 1024);
    }
    if (wave < 2) {
      const float* g = ws_nb
          + (size_t)((n * 128 + ty0 + 2 * wave + (lane >> 5)) * 128)
          + tx0 + (lane & 31);
      g2lds4(g, (char*)nbt[b] + wave * 256);
    } else {                                 // dummy keeps per-wave count = 10
      const float* g = ws_nb
          + (size_t)((n * 128 + ty0 + (lane >> 5)) * 128) + (lane & 31);
      g2lds4(g, (char*)dmy + (wave - 2) * 256);
    }
  };

  issue_unit(0, 0);                          // prologue: j=0 into buf 0

  for (int j = 0; j < 4; ++j) {
    const int tx0 = j * 32;
    const int cur = j & 1;

    if (j == 0) { asm volatile("s_waitcnt vmcnt(0)" ::: "memory"); }
    else        { asm volatile("s_waitcnt vmcnt(4)" ::: "memory"); }
    __builtin_amdgcn_sched_barrier(0);
    __builtin_amdgcn_s_barrier();            // all waves' DMA for buf cur done
    __builtin_amdgcn_sched_barrier(0);

    if (j < 3) issue_unit(tx0 + 32, cur ^ 1);  // overlaps compute + stores

    // acc init from NB (rows=px after operand swap); wave owns row `wave`
    const f32x4 nbv0 = *(const f32x4*)&nbt[cur][wave * 32 + 0  + hi * 4];
    const f32x4 nbv1 = *(const f32x4*)&nbt[cur][wave * 32 + 16 + hi * 4];
    f32x4 acc00 = nbv0, acc01 = nbv1;        // cbl0: h0, h1
    f32x4 acc10 = nbv0, acc11 = nbv1;        // cbl1: h0, h1

    short8 Aaf0, Aaf1;
    short8 Baf0, Baf1;
    short8 Caf0, Caf1;

#define LOADSET(P, K) { \
      constexpr int tap_ = (K) >> 1, ks_ = (K) & 1; \
      constexpr int ty_ = (tap_ / 3) * 2, tx_ = (tap_ % 3) * 2; \
      const int p0_ = (wave + ty_) * 36 + (lo + tx_); \
      const int p1_ = p0_ + 16; \
      P##af0 = halo[cur][p0_ * 8 + ((ks_ * 4 + hi) ^ (p0_ & 7))]; \
      P##af1 = halo[cur][p1_ * 8 + ((ks_ * 4 + hi) ^ (p1_ & 7))]; \
    }
#define MFMASET(P, K) { \
      constexpr int tap_ = (K) >> 1, ks_ = (K) & 1; \
      acc00 = __builtin_amdgcn_mfma_f32_16x16x32_bf16(P##af0, W[tap_ * 4 + 0 + ks_], acc00, 0, 0, 0); \
      acc01 = __builtin_amdgcn_mfma_f32_16x16x32_bf16(P##af1, W[tap_ * 4 + 0 + ks_], acc01, 0, 0, 0); \
      acc10 = __builtin_amdgcn_mfma_f32_16x16x32_bf16(P##af0, W[tap_ * 4 + 2 + ks_], acc10, 0, 0, 0); \
      acc11 = __builtin_amdgcn_mfma_f32_16x16x32_bf16(P##af1, W[tap_ * 4 + 2 + ks_], acc11, 0, 0, 0); \
    }

    LOADSET(A, 0); LOADSET(B, 1);
    LOADSET(C, 2);  MFMASET(A, 0);
    LOADSET(A, 3);  MFMASET(B, 1);
    LOADSET(B, 4);  MFMASET(C, 2);
    LOADSET(C, 5);  MFMASET(A, 3);
    LOADSET(A, 6);  MFMASET(B, 4);
    LOADSET(B, 7);  MFMASET(C, 5);
    LOADSET(C, 8);  MFMASET(A, 6);
    LOADSET(A, 9);  MFMASET(B, 7);
    LOADSET(B, 10); MFMASET(C, 8);
    LOADSET(C, 11); MFMASET(A, 9);
    LOADSET(A, 12); MFMASET(B, 10);
    LOADSET(B, 13); MFMASET(C, 11);
    LOADSET(C, 14); MFMASET(A, 12);
    LOADSET(A, 15); MFMASET(B, 13);
    LOADSET(B, 16); MFMASET(C, 14);
    LOADSET(C, 17); MFMASET(A, 15);
    MFMASET(B, 16);
    MFMASET(C, 17);
#undef LOADSET
#undef MFMASET

    // stores: 4 instrs/wave, full 128B lines; left in flight across barrier
    {
      const int gy = ty0 + wave;
      const int gx0 = tx0 + hi * 4;
      const int co0 = cob * 32 + lo;
      *(f32x4*)&out[(((size_t)n * CO + co0) * HH + gy) * WW + gx0] = acc00;
      *(f32x4*)&out[(((size_t)n * CO + co0) * HH + gy) * WW + gx0 + 16] = acc01;
      *(f32x4*)&out[(((size_t)n * CO + co0 + 16) * HH + gy) * WW + gx0] = acc10;
      *(f32x4*)&out[(((size_t)n * CO + co0 + 16) * HH + gy) * WW + gx0 + 16] = acc11;
    }
  }
}

// ================= SAFE PATH (Round-2 proven, 705 KB ws) =================
__global__ __launch_bounds__(256) void prep_kernel_safe(
    const float* __restrict__ in, const float* __restrict__ w,
    unsigned short* __restrict__ ws_w, float* __restrict__ ws_T) {
  const int bid = blockIdx.x, tid = threadIdx.x;
  if (bid < 288) {
    const int el = bid * 256 + tid;
    const int tap = el >> 13;
    const int rem = el & 8191;
    const int co = rem >> 6, ic = rem & 63;
    const int ky = (tap / 3) * 2, kx = (tap % 3) * 2;
    ws_w[el] = f2bf(w[(co * 64 + ic) * 25 + ky * 5 + kx]);
  } else {
    const int p = (bid - 288) * 256 + tid;
    const int n = p >> 14;
    const int yx = p & 16383;
    const float* base = in + (size_t)n * CI * (HH * WW) + yx;
    float s = 0.f;
    #pragma unroll
    for (int ic = 0; ic < CI; ++ic) s += base[ic * (HH * WW)];
    ws_T[p] = s;
  }
}

#define SHR 12
#define SHC 36
#define SNPOS (SHR * SHC)

__global__ __launch_bounds__(256, 2) void conv_kernel_safe(
    const float* __restrict__ in, const unsigned short* __restrict__ ws_w,
    const float* __restrict__ ws_T, float* __restrict__ out) {
  __shared__ short8 in_lds[SNPOS * 8];
  __shared__ float T_lds[SNPOS];

  const int tid = threadIdx.x;
  const int t = blockIdx.x;
  const int n = blockIdx.y;
  const int ty0 = (t >> 2) * 8;
  const int tx0 = (t & 3) * 32;

  for (int e = tid; e < SNPOS * 8; e += 256) {
    const int slot = e / SNPOS;
    const int pos = e - slot * SNPOS;
    const int r = pos / SHC, c = pos - r * SHC;
    const int gy = ty0 + r - 2, gx = tx0 + c - 2;
    const bool ok = (gy >= 0 && gy < HH && gx >= 0 && gx < WW);
    const long off = ((long)(n * CI + slot * 8) * HH + gy) * WW + gx;
    short8 pk;
    #pragma unroll
    for (int j = 0; j < 8; ++j) {
      const float v = ok ? in[off + (long)j * (HH * WW)] : 0.f;
      pk[j] = (short)f2bf(v);
    }
    in_lds[pos * 8 + (slot ^ (pos & 7))] = pk;
  }
  for (int e = tid; e < SNPOS; e += 256) {
    const int r = e / SHC, c = e - r * SHC;
    const int gy = ty0 + r - 2, gx = tx0 + c - 2;
    T_lds[e] = (gy >= 0 && gy < HH && gx >= 0 && gx < WW)
                   ? ws_T[((size_t)n * HH + gy) * WW + gx] : 0.f;
  }
  __syncthreads();

  const int wave = tid >> 6;
  const int lane = tid & 63;
  const int lo = lane & 15;
  const int hi = lane >> 4;

  int py[4], pxc[4];
  #pragma unroll
  for (int f = 0; f < 4; ++f) {
    const int pb = wave * 64 + f * 16;
    py[f] = pb >> 5;
    pxc[f] = (pb & 31) + lo;
  }

  f32x4 acc[8][4];
  #pragma unroll
  for (int cb = 0; cb < 8; ++cb)
    #pragma unroll
    for (int f = 0; f < 4; ++f) acc[cb][f] = (f32x4){0.f, 0.f, 0.f, 0.f};

  const short8* wsv = (const short8*)ws_w;

  #pragma unroll
  for (int tap = 0; tap < 9; ++tap) {
    const int ty = (tap / 3) * 2, tx = (tap % 3) * 2;
    #pragma unroll
    for (int ks = 0; ks < 2; ++ks) {
      short8 bfrag[4];
      #pragma unroll
      for (int f = 0; f < 4; ++f) {
        const int pos = (py[f] + ty) * SHC + (pxc[f] + tx);
        bfrag[f] = in_lds[pos * 8 + ((ks * 4 + hi) ^ (pos & 7))];
      }
      #pragma unroll
      for (int cb = 0; cb < 8; ++cb) {
        const short8 afrag = wsv[(tap * 128 + cb * 16 + lo) * 8 + ks * 4 + hi];
        #pragma unroll
        for (int f = 0; f < 4; ++f)
          acc[cb][f] = __builtin_amdgcn_mfma_f32_16x16x32_bf16(
              afrag, bfrag[f], acc[cb][f], 0, 0, 0);
      }
    }
  }

  float nb[4];
  #pragma unroll
  for (int f = 0; f < 4; ++f) {
    float s = 0.f;
    #pragma unroll
    for (int ky = 0; ky < 5; ++ky)
      #pragma unroll
      for (int kx = 0; kx < 5; ++kx)
        if ((ky & 1) | (kx & 1))
          s += T_lds[(py[f] + ky) * SHC + (pxc[f] + kx)];
    nb[f] = s * MU;
  }

  #pragma unroll
  for (int cb = 0; cb < 8; ++cb) {
    #pragma unroll
    for (int f = 0; f < 4; ++f) {
      const int gy = ty0 + py[f];
      const int gx = tx0 + pxc[f];
      #pragma unroll
      for (int q = 0; q < 4; ++q) {
        const int co = cb * 16 + hi * 4 + q;
        out[(((size_t)n * CO + co) * HH + gy) * WW + gx] = acc[cb][f][q] + nb[f];
      }
    }
  }
}

extern "C" void kernel_launch(void* const* d_in, const int* in_sizes, int n_in,
                              void* d_out, int out_size, void* d_ws, size_t ws_size,
                              hipStream_t stream) {
  const float* in = (const float*)d_in[0];
  const float* w  = (const float*)d_in[1];
  float* out = (float*)d_out;
  unsigned short* ws_w = (unsigned short*)d_ws;

  if (ws_size >= WS_TOTAL) {
    float* ws_T = (float*)((char*)d_ws + WS_T_OFF);
    short8* ws_x = (short8*)((char*)d_ws + WS_X_OFF);
    float* ws_nb = (float*)((char*)d_ws + WS_NB_OFF);
    prep_kernel<<<dim3(556), 256, 0, stream>>>(in, w, ws_w, ws_T, ws_x);
    nb_kernel<<<dim3(512), 256, 0, stream>>>(ws_T, ws_nb);
    conv_kernel<<<dim3(1024), 256, 0, stream>>>(
        ws_w, ws_nb, (const unsigned short*)ws_x, out);
  } else {
    float* ws_T = (float*)((char*)d_ws + WS_W_BYTES);
    prep_kernel_safe<<<dim3(288 + 512), 256, 0, stream>>>(in, w, ws_w, ws_T);
    conv_kernel_safe<<<dim3(64, NN), 256, 0, stream>>>(in, ws_w, ws_T, out);
  }
}

// Round 23
// 43.981 us; speedup vs baseline: 1.0481x; 1.0481x over previous
//
#include <hip/hip_runtime.h>

typedef short short8 __attribute__((ext_vector_type(8)));
typedef float f32x4 __attribute__((ext_vector_type(4)));

#define NN 8
#define CI 64
#define CO 128
#define HH 128
#define WW 128
#define PH 132             // padded (2-halo each side)
#define PW 132
#define MU 0.033333333333333333f

#define WS_W_BYTES (9 * 128 * 64 * 2)        // 147456
#define WS_T_OFF   WS_W_BYTES
#define WS_T_BYTES (NN * PH * PW * 4)        // 557568
#define WS_X_OFF   (WS_T_OFF + WS_T_BYTES)   // 705024
#define WS_X_BYTES ((size_t)NN * PH * PW * CI * 2)   // 17842176
#define WS_NB_OFF  (WS_X_OFF + WS_X_BYTES)   // 18547200
#define WS_TOTAL   (WS_NB_OFF + WS_T_BYTES)  // ~19.1 MB

__device__ __forceinline__ unsigned short f2bf(float f) {
  unsigned u = __float_as_uint(f);
  u += 0x7fffu + ((u >> 16) & 1u);     // round-to-nearest-even
  return (unsigned short)(u >> 16);
}

__device__ __forceinline__ void g2lds16(const void* g, void* l) {
  __builtin_amdgcn_global_load_lds(
      (const __attribute__((address_space(1))) unsigned int*)g,
      (__attribute__((address_space(3))) unsigned int*)l, 16, 0, 0);
}
__device__ __forceinline__ void g2lds4(const void* g, void* l) {
  __builtin_amdgcn_global_load_lds(
      (const __attribute__((address_space(1))) unsigned int*)g,
      (__attribute__((address_space(3))) unsigned int*)l, 4, 0, 0);
}

// ================= FAST PATH =================
// prep: bf16 NHWC padded repack + channel-sum plane T + weights (coalesced
// layout: ws_w[(tap*16 + cb*2 + ks)*64 + lane] short8, lane=hi*16+lo holds
// w[co=cb*16+lo][ic=ks*32+hi*8+j], even taps only). ws_x is PLAIN NHWC
// [n][y][x][ic] bf16 (128 B per pixel; the lx XOR pair cancels).
__global__ __launch_bounds__(256) void prep_kernel(
    const float* __restrict__ in, const float* __restrict__ w,
    unsigned short* __restrict__ ws_w, float* __restrict__ ws_T,
    short8* __restrict__ ws_x) {
  const int b = blockIdx.x, tid = threadIdx.x;
  if (b < 512) {
    __shared__ short8 lx[256][8];            // [px][slot^(px&7)]
    const int n = b >> 6, pair = b & 63;
    const int px = tid;
    const int r = pair * 2 + (px >> 7), x = px & 127;
    const float* src = in + ((size_t)(n * CI) * HH + r) * WW + x;
    float tsum = 0.f;
    #pragma unroll
    for (int g = 0; g < 8; ++g) {
      short8 pk;
      #pragma unroll
      for (int j = 0; j < 8; ++j) {
        const float v = src[(size_t)(g * 8 + j) * (HH * WW)];
        tsum += v;
        pk[j] = (short)f2bf(v);
      }
      lx[px][g ^ (px & 7)] = pk;
    }
    ws_T[(n * PH + r + 2) * PW + (x + 2)] = tsum;
    __syncthreads();
    #pragma unroll
    for (int it = 0; it < 8; ++it) {         // coalesced NHWC store, 16B/lane
      const int G = it * 256 + tid;
      const int px2 = G >> 3, g2 = G & 7;
      const int r2 = pair * 2 + (px2 >> 7), x2 = px2 & 127;
      ws_x[((size_t)(n * PH + r2 + 2) * PW + (x2 + 2)) * 8 + g2] =
          lx[px2][g2 ^ (px2 & 7)];
    }
  } else if (b < 520) {                      // zero the padded borders
    const int n = b - 512;
    const short8 z = {0, 0, 0, 0, 0, 0, 0, 0};
    for (int e = tid; e < 1040 * 8; e += 256) {
      const int px = e >> 3, g = e & 7;
      int y, x;
      if (px < 528) { const int r4 = px / 132; y = (r4 < 2) ? r4 : r4 + 128; x = px - r4 * 132; }
      else { const int q = px - 528; const int c4 = q >> 7; x = (c4 < 2) ? c4 : c4 + 128; y = 2 + (q & 127); }
      ws_x[((size_t)(n * PH + y) * PW + x) * 8 + g] = z;
    }
    for (int e = tid; e < 1040; e += 256) {
      int y, x;
      if (e < 528) { const int r4 = e / 132; y = (r4 < 2) ? r4 : r4 + 128; x = e - r4 * 132; }
      else { const int q = e - 528; const int c4 = q >> 7; x = (c4 < 2) ? c4 : c4 + 128; y = 2 + (q & 127); }
      ws_T[(n * PH + y) * PW + x] = 0.f;
    }
  } else {                                   // weights, coalesced MFMA layout
    const int el = (b - 520) * 256 + tid;    // 0..9215 short8 elements
    const int lane = el & 63;
    const int idx = el >> 6;                 // 0..143 = tap*16 + cb*2 + ks
    const int ks = idx & 1, cb = (idx >> 1) & 7, tap = idx >> 4;
    const int lo = lane & 15, hi = lane >> 4;
    const int ky = (tap / 3) * 2, kx = (tap % 3) * 2;
    const float* wp = w + (size_t)((cb * 16 + lo) * 64 + ks * 32 + hi * 8) * 25
                        + ky * 5 + kx;
    short8 pk;
    #pragma unroll
    for (int j = 0; j < 8; ++j) pk[j] = (short)f2bf(wp[j * 25]);
    ((short8*)ws_w)[el] = pk;
  }
}

// nb: per-pixel neighbor plane, COMPACT [n][128][128] (16B-aligned reads)
__global__ __launch_bounds__(256) void nb_kernel(
    const float* __restrict__ ws_T, float* __restrict__ ws_nb) {
  const int p = blockIdx.x * 256 + threadIdx.x;   // 131072 interior pixels
  const int n = p >> 14, yx = p & 16383;
  const int y = yx >> 7, x = yx & 127;
  const float* Tb = ws_T + (size_t)(n * PH + y) * PW + x;
  float s = 0.f;
  #pragma unroll
  for (int ky = 0; ky < 5; ++ky)
    #pragma unroll
    for (int kx = 0; kx < 5; ++kx)
      if ((ky & 1) | (kx & 1)) s += Tb[ky * PW + kx];
  ws_nb[(size_t)p] = s * MU;
}

// conv v14: v12's exact inner structure, regridded to 512 blocks = exactly
// 2/CU (single full-residency round, no tail, no second-round restart).
// Each block owns an 8-row x 128-col x 32-co slab (8 j-subtiles), so the
// W[36] register load happens half as often. XCD-pinned n=bid&7 kept.
__global__ __launch_bounds__(256)
__attribute__((amdgpu_waves_per_eu(2, 2)))
void conv_kernel(
    const unsigned short* __restrict__ ws_w, const float* __restrict__ ws_nb,
    const unsigned short* __restrict__ ws_x, float* __restrict__ out) {
  __shared__ short8 halo[288 * 8];     // 36864 B: 8 rows x 36 cols, swizzled
  __shared__ float  nbt[128];          // 512 B: 4 rows x 32 cols

  const int tid = threadIdx.x;
  const int wave = tid >> 6, lane = tid & 63;
  const int bid = blockIdx.x;          // 512 = (ystrip2*4 + quarter)*8 + n
  const int n = bid & 7;
  const int rest = bid >> 3;
  const int cob = rest & 3;            // co-quarter
  const int Y0 = (rest >> 2) * 8;      // 16 y-slabs of 8 rows
  const int lo = lane & 15, hi = lane >> 4;

  // quarter weights -> registers once (36 coalesced b128, L2-hot; static idx)
  const short8* wsv = (const short8*)ws_w;
  short8 W[36];                        // [tap*4 + cbl*2 + ks]
  #pragma unroll
  for (int k = 0; k < 36; ++k)
    W[k] = wsv[((k >> 2) * 16 + cob * 4 + (k & 3)) * 64 + lane];

  for (int j = 0; j < 8; ++j) {
    const int ty0 = Y0 + (j >> 2) * 4;       // 2 y-substrips
    const int tx0 = (j & 3) * 32;            // 4 x-subtiles

    // halo DMA: 36 x 1KB chunks (9 per wave), source pre-swizzled
    for (int k = wave; k < 36; k += 4) {
      const int pos = k * 8 + (lane >> 3);
      const int r = pos / 36, c = pos - r * 36;
      const int chunk = (lane & 7) ^ (pos & 7);
      const unsigned short* g =
          ws_x + ((size_t)(n * PH + ty0 + r) * PW + (tx0 + c)) * 64 + chunk * 8;
      g2lds16(g, (char*)halo + k * 1024);
    }
    if (wave < 2) {                          // nb tile (compact plane)
      const float* g = ws_nb
          + (size_t)((n * 128 + ty0 + 2 * wave + (lane >> 5)) * 128)
          + tx0 + (lane & 31);
      g2lds4(g, (char*)nbt + wave * 256);
    }
    __syncthreads();                         // drains vmcnt (DMA complete)

    // acc init from NB (rows=px after operand swap); wave owns row `wave`
    const f32x4 nbv0 = *(const f32x4*)&nbt[wave * 32 + 0  + hi * 4];
    const f32x4 nbv1 = *(const f32x4*)&nbt[wave * 32 + 16 + hi * 4];
    f32x4 acc00 = nbv0, acc01 = nbv1;        // cbl0: h0, h1
    f32x4 acc10 = nbv0, acc11 = nbv1;        // cbl1: h0, h1

    short8 Aaf0, Aaf1;
    short8 Baf0, Baf1;
    short8 Caf0, Caf1;

#define LOADSET(P, K) { \
      constexpr int tap_ = (K) >> 1, ks_ = (K) & 1; \
      constexpr int ty_ = (tap_ / 3) * 2, tx_ = (tap_ % 3) * 2; \
      const int p0_ = (wave + ty_) * 36 + (lo + tx_); \
      const int p1_ = p0_ + 16; \
      P##af0 = halo[p0_ * 8 + ((ks_ * 4 + hi) ^ (p0_ & 7))]; \
      P##af1 = halo[p1_ * 8 + ((ks_ * 4 + hi) ^ (p1_ & 7))]; \
    }
#define MFMASET(P, K) { \
      constexpr int tap_ = (K) >> 1, ks_ = (K) & 1; \
      acc00 = __builtin_amdgcn_mfma_f32_16x16x32_bf16(P##af0, W[tap_ * 4 + 0 + ks_], acc00, 0, 0, 0); \
      acc01 = __builtin_amdgcn_mfma_f32_16x16x32_bf16(P##af1, W[tap_ * 4 + 0 + ks_], acc01, 0, 0, 0); \
      acc10 = __builtin_amdgcn_mfma_f32_16x16x32_bf16(P##af0, W[tap_ * 4 + 2 + ks_], acc10, 0, 0, 0); \
      acc11 = __builtin_amdgcn_mfma_f32_16x16x32_bf16(P##af1, W[tap_ * 4 + 2 + ks_], acc11, 0, 0, 0); \
    }

    LOADSET(A, 0); LOADSET(B, 1);
    LOADSET(C, 2);  MFMASET(A, 0);
    LOADSET(A, 3);  MFMASET(B, 1);
    LOADSET(B, 4);  MFMASET(C, 2);
    LOADSET(C, 5);  MFMASET(A, 3);
    LOADSET(A, 6);  MFMASET(B, 4);
    LOADSET(B, 7);  MFMASET(C, 5);
    LOADSET(C, 8);  MFMASET(A, 6);
    LOADSET(A, 9);  MFMASET(B, 7);
    LOADSET(B, 10); MFMASET(C, 8);
    LOADSET(C, 11); MFMASET(A, 9);
    LOADSET(A, 12); MFMASET(B, 10);
    LOADSET(B, 13); MFMASET(C, 11);
    LOADSET(C, 14); MFMASET(A, 12);
    LOADSET(A, 15); MFMASET(B, 13);
    LOADSET(B, 16); MFMASET(C, 14);
    LOADSET(C, 17); MFMASET(A, 15);
    MFMASET(B, 16);
    MFMASET(C, 17);
#undef LOADSET
#undef MFMASET

    // stores: h0+h1 cover the full 32-px row -> whole 128B lines per block;
    // after the 4 x-subtiles each (co,row) 512B row is fully written.
    {
      const int gy = ty0 + wave;
      const int gx0 = tx0 + hi * 4;
      const int co0 = cob * 32 + lo;
      *(f32x4*)&out[(((size_t)n * CO + co0) * HH + gy) * WW + gx0] = acc00;
      *(f32x4*)&out[(((size_t)n * CO + co0) * HH + gy) * WW + gx0 + 16] = acc01;
      *(f32x4*)&out[(((size_t)n * CO + co0 + 16) * HH + gy) * WW + gx0] = acc10;
      *(f32x4*)&out[(((size_t)n * CO + co0 + 16) * HH + gy) * WW + gx0 + 16] = acc11;
    }
    __syncthreads();                         // protect halo/nbt overwrite
  }
}

// ================= SAFE PATH (Round-2 proven, 705 KB ws) =================
__global__ __launch_bounds__(256) void prep_kernel_safe(
    const float* __restrict__ in, const float* __restrict__ w,
    unsigned short* __restrict__ ws_w, float* __restrict__ ws_T) {
  const int bid = blockIdx.x, tid = threadIdx.x;
  if (bid < 288) {
    const int el = bid * 256 + tid;
    const int tap = el >> 13;
    const int rem = el & 8191;
    const int co = rem >> 6, ic = rem & 63;
    const int ky = (tap / 3) * 2, kx = (tap % 3) * 2;
    ws_w[el] = f2bf(w[(co * 64 + ic) * 25 + ky * 5 + kx]);
  } else {
    const int p = (bid - 288) * 256 + tid;
    const int n = p >> 14;
    const int yx = p & 16383;
    const float* base = in + (size_t)n * CI * (HH * WW) + yx;
    float s = 0.f;
    #pragma unroll
    for (int ic = 0; ic < CI; ++ic) s += base[ic * (HH * WW)];
    ws_T[p] = s;
  }
}

#define SHR 12
#define SHC 36
#define SNPOS (SHR * SHC)

__global__ __launch_bounds__(256, 2) void conv_kernel_safe(
    const float* __restrict__ in, const unsigned short* __restrict__ ws_w,
    const float* __restrict__ ws_T, float* __restrict__ out) {
  __shared__ short8 in_lds[SNPOS * 8];
  __shared__ float T_lds[SNPOS];

  const int tid = threadIdx.x;
  const int t = blockIdx.x;
  const int n = blockIdx.y;
  const int ty0 = (t >> 2) * 8;
  const int tx0 = (t & 3) * 32;

  for (int e = tid; e < SNPOS * 8; e += 256) {
    const int slot = e / SNPOS;
    const int pos = e - slot * SNPOS;
    const int r = pos / SHC, c = pos - r * SHC;
    const int gy = ty0 + r - 2, gx = tx0 + c - 2;
    const bool ok = (gy >= 0 && gy < HH && gx >= 0 && gx < WW);
    const long off = ((long)(n * CI + slot * 8) * HH + gy) * WW + gx;
    short8 pk;
    #pragma unroll
    for (int j = 0; j < 8; ++j) {
      const float v = ok ? in[off + (long)j * (HH * WW)] : 0.f;
      pk[j] = (short)f2bf(v);
    }
    in_lds[pos * 8 + (slot ^ (pos & 7))] = pk;
  }
  for (int e = tid; e < SNPOS; e += 256) {
    const int r = e / SHC, c = e - r * SHC;
    const int gy = ty0 + r - 2, gx = tx0 + c - 2;
    T_lds[e] = (gy >= 0 && gy < HH && gx >= 0 && gx < WW)
                   ? ws_T[((size_t)n * HH + gy) * WW + gx] : 0.f;
  }
  __syncthreads();

  const int wave = tid >> 6;
  const int lane = tid & 63;
  const int lo = lane & 15;
  const int hi = lane >> 4;

  int py[4], pxc[4];
  #pragma unroll
  for (int f = 0; f < 4; ++f) {
    const int pb = wave * 64 + f * 16;
    py[f] = pb >> 5;
    pxc[f] = (pb & 31) + lo;
  }

  f32x4 acc[8][4];
  #pragma unroll
  for (int cb = 0; cb < 8; ++cb)
    #pragma unroll
    for (int f = 0; f < 4; ++f) acc[cb][f] = (f32x4){0.f, 0.f, 0.f, 0.f};

  const short8* wsv = (const short8*)ws_w;

  #pragma unroll
  for (int tap = 0; tap < 9; ++tap) {
    const int ty = (tap / 3) * 2, tx = (tap % 3) * 2;
    #pragma unroll
    for (int ks = 0; ks < 2; ++ks) {
      short8 bfrag[4];
      #pragma unroll
      for (int f = 0; f < 4; ++f) {
        const int pos = (py[f] + ty) * SHC + (pxc[f] + tx);
        bfrag[f] = in_lds[pos * 8 + ((ks * 4 + hi) ^ (pos & 7))];
      }
      #pragma unroll
      for (int cb = 0; cb < 8; ++cb) {
        const short8 afrag = wsv[(tap * 128 + cb * 16 + lo) * 8 + ks * 4 + hi];
        #pragma unroll
        for (int f = 0; f < 4; ++f)
          acc[cb][f] = __builtin_amdgcn_mfma_f32_16x16x32_bf16(
              afrag, bfrag[f], acc[cb][f], 0, 0, 0);
      }
    }
  }

  float nb[4];
  #pragma unroll
  for (int f = 0; f < 4; ++f) {
    float s = 0.f;
    #pragma unroll
    for (int ky = 0; ky < 5; ++ky)
      #pragma unroll
      for (int kx = 0; kx < 5; ++kx)
        if ((ky & 1) | (kx & 1))
          s += T_lds[(py[f] + ky) * SHC + (pxc[f] + kx)];
    nb[f] = s * MU;
  }

  #pragma unroll
  for (int cb = 0; cb < 8; ++cb) {
    #pragma unroll
    for (int f = 0; f < 4; ++f) {
      const int gy = ty0 + py[f];
      const int gx = tx0 + pxc[f];
      #pragma unroll
      for (int q = 0; q < 4; ++q) {
        const int co = cb * 16 + hi * 4 + q;
        out[(((size_t)n * CO + co) * HH + gy) * WW + gx] = acc[cb][f][q] + nb[f];
      }
    }
  }
}

extern "C" void kernel_launch(void* const* d_in, const int* in_sizes, int n_in,
                              void* d_out, int out_size, void* d_ws, size_t ws_size,
                              hipStream_t stream) {
  const float* in = (const float*)d_in[0];
  const float* w  = (const float*)d_in[1];
  float* out = (float*)d_out;
  unsigned short* ws_w = (unsigned short*)d_ws;

  if (ws_size >= WS_TOTAL) {
    float* ws_T = (float*)((char*)d_ws + WS_T_OFF);
    short8* ws_x = (short8*)((char*)d_ws + WS_X_OFF);
    float* ws_nb = (float*)((char*)d_ws + WS_NB_OFF);
    prep_kernel<<<dim3(556), 256, 0, stream>>>(in, w, ws_w, ws_T, ws_x);
    nb_kernel<<<dim3(512), 256, 0, stream>>>(ws_T, ws_nb);
    conv_kernel<<<dim3(512), 256, 0, stream>>>(
        ws_w, ws_nb, (const unsigned short*)ws_x, out);
  } else {
    float* ws_T = (float*)((char*)d_ws + WS_W_BYTES);
    prep_kernel_safe<<<dim3(288 + 512), 256, 0, stream>>>(in, w, ws_w, ws_T);
    conv_kernel_safe<<<dim3(64, NN), 256, 0, stream>>>(in, ws_w, ws_T, out);
  }
}

// Round 24
// 43.672 us; speedup vs baseline: 1.0556x; 1.0071x over previous
//
#include <hip/hip_runtime.h>

typedef short short8 __attribute__((ext_vector_type(8)));
typedef float f32x4 __attribute__((ext_vector_type(4)));
typedef float f32x2 __attribute__((ext_vector_type(2)));

#define NN 8
#define CI 64
#define CO 128
#define HH 128
#define WW 128
#define PH 132             // padded (2-halo each side)
#define PW 132
#define MU 0.033333333333333333f

#define WS_W_BYTES (9 * 128 * 64 * 2)        // 147456
#define WS_T_OFF   WS_W_BYTES
#define WS_T_BYTES (NN * PH * PW * 4)        // 557568
#define WS_X_OFF   (WS_T_OFF + WS_T_BYTES)   // 705024
#define WS_X_BYTES ((size_t)NN * PH * PW * CI * 2)   // 17842176
#define WS_NB_OFF  (WS_X_OFF + WS_X_BYTES)   // 18547200
#define WS_TOTAL   (WS_NB_OFF + WS_T_BYTES)  // ~19.1 MB

__device__ __forceinline__ unsigned short f2bf(float f) {
  unsigned u = __float_as_uint(f);
  u += 0x7fffu + ((u >> 16) & 1u);     // round-to-nearest-even
  return (unsigned short)(u >> 16);
}

__device__ __forceinline__ void g2lds16(const void* g, void* l) {
  __builtin_amdgcn_global_load_lds(
      (const __attribute__((address_space(1))) unsigned int*)g,
      (__attribute__((address_space(3))) unsigned int*)l, 16, 0, 0);
}
__device__ __forceinline__ void g2lds4(const void* g, void* l) {
  __builtin_amdgcn_global_load_lds(
      (const __attribute__((address_space(1))) unsigned int*)g,
      (__attribute__((address_space(3))) unsigned int*)l, 4, 0, 0);
}

// ================= FAST PATH =================
// prep v2: pixel path vectorized — each thread owns 2 adjacent x, loads
// float2 per channel (64 loads -> 512B/wave requests), 4-row x 128-col
// tiles (512 px, 64KB LDS transpose). ws_x PLAIN NHWC [n][y][x][ic] bf16;
// weights coalesced MFMA layout (unchanged); T float2 store.
__global__ __launch_bounds__(256) void prep_kernel(
    const float* __restrict__ in, const float* __restrict__ w,
    unsigned short* __restrict__ ws_w, float* __restrict__ ws_T,
    short8* __restrict__ ws_x) {
  const int b = blockIdx.x, tid = threadIdx.x;
  if (b < 256) {                             // 256 blocks x 512 px
    __shared__ short8 lx[512][8];            // [px][slot^(px&7)], 64KB
    const int n = b >> 5, quad = b & 31;     // 32 row-quads
    const int rl = tid >> 6;                 // row 0..3
    const int x2 = (tid & 63) * 2;           // even x
    const int r = quad * 4 + rl;
    const float* src = in + ((size_t)(n * CI) * HH + r) * WW + x2;
    const int px0 = rl * 128 + x2;
    float ts0 = 0.f, ts1 = 0.f;
    #pragma unroll
    for (int g = 0; g < 8; ++g) {
      short8 pk0, pk1;
      #pragma unroll
      for (int j = 0; j < 8; ++j) {
        const f32x2 v = *(const f32x2*)(src + (size_t)(g * 8 + j) * (HH * WW));
        ts0 += v[0]; ts1 += v[1];
        pk0[j] = (short)f2bf(v[0]);
        pk1[j] = (short)f2bf(v[1]);
      }
      lx[px0][g ^ (px0 & 7)] = pk0;
      lx[px0 + 1][g ^ ((px0 + 1) & 7)] = pk1;
    }
    *(f32x2*)&ws_T[(n * PH + r + 2) * PW + (x2 + 2)] = (f32x2){ts0, ts1};
    __syncthreads();
    #pragma unroll
    for (int it = 0; it < 16; ++it) {        // coalesced NHWC store, 16B/lane
      const int G = it * 256 + tid;
      const int px2 = G >> 3, g2 = G & 7;
      const int r2 = quad * 4 + (px2 >> 7), x2b = px2 & 127;
      ws_x[((size_t)(n * PH + r2 + 2) * PW + (x2b + 2)) * 8 + g2] =
          lx[px2][g2 ^ (px2 & 7)];
    }
  } else if (b < 264) {                      // zero the padded borders
    const int n = b - 256;
    const short8 z = {0, 0, 0, 0, 0, 0, 0, 0};
    for (int e = tid; e < 1040 * 8; e += 256) {
      const int px = e >> 3, g = e & 7;
      int y, x;
      if (px < 528) { const int r4 = px / 132; y = (r4 < 2) ? r4 : r4 + 128; x = px - r4 * 132; }
      else { const int q = px - 528; const int c4 = q >> 7; x = (c4 < 2) ? c4 : c4 + 128; y = 2 + (q & 127); }
      ws_x[((size_t)(n * PH + y) * PW + x) * 8 + g] = z;
    }
    for (int e = tid; e < 1040; e += 256) {
      int y, x;
      if (e < 528) { const int r4 = e / 132; y = (r4 < 2) ? r4 : r4 + 128; x = e - r4 * 132; }
      else { const int q = e - 528; const int c4 = q >> 7; x = (c4 < 2) ? c4 : c4 + 128; y = 2 + (q & 127); }
      ws_T[(n * PH + y) * PW + x] = 0.f;
    }
  } else {                                   // weights, coalesced MFMA layout
    const int el = (b - 264) * 256 + tid;    // 0..9215 short8 elements
    const int lane = el & 63;
    const int idx = el >> 6;                 // 0..143 = tap*16 + cb*2 + ks
    const int ks = idx & 1, cb = (idx >> 1) & 7, tap = idx >> 4;
    const int lo = lane & 15, hi = lane >> 4;
    const int ky = (tap / 3) * 2, kx = (tap % 3) * 2;
    const float* wp = w + (size_t)((cb * 16 + lo) * 64 + ks * 32 + hi * 8) * 25
                        + ky * 5 + kx;
    short8 pk;
    #pragma unroll
    for (int j = 0; j < 8; ++j) pk[j] = (short)f2bf(wp[j * 25]);
    ((short8*)ws_w)[el] = pk;
  }
}

// nb: per-pixel neighbor plane, COMPACT [n][128][128] (16B-aligned reads)
__global__ __launch_bounds__(256) void nb_kernel(
    const float* __restrict__ ws_T, float* __restrict__ ws_nb) {
  const int p = blockIdx.x * 256 + threadIdx.x;   // 131072 interior pixels
  const int n = p >> 14, yx = p & 16383;
  const int y = yx >> 7, x = yx & 127;
  const float* Tb = ws_T + (size_t)(n * PH + y) * PW + x;
  float s = 0.f;
  #pragma unroll
  for (int ky = 0; ky < 5; ++ky)
    #pragma unroll
    for (int kx = 0; kx < 5; ++kx)
      if ((ky & 1) | (kx & 1)) s += Tb[ky * PW + kx];
  ws_nb[(size_t)p] = s * MU;
}

// conv v14 (R23-proven, 44.0us): 512 blocks = exactly 2/CU, single full
// residency round; block owns 8-row x 128-col x 32-co slab (8 j-subtiles);
// W[36] in registers (waves_per_eu(2,2) pins 256-VGPR budget); XCD-pinned
// n=bid&7; 3-deep af software pipeline; full-128B-line dwordx4 stores.
__global__ __launch_bounds__(256)
__attribute__((amdgpu_waves_per_eu(2, 2)))
void conv_kernel(
    const unsigned short* __restrict__ ws_w, const float* __restrict__ ws_nb,
    const unsigned short* __restrict__ ws_x, float* __restrict__ out) {
  __shared__ short8 halo[288 * 8];     // 36864 B: 8 rows x 36 cols, swizzled
  __shared__ float  nbt[128];          // 512 B: 4 rows x 32 cols

  const int tid = threadIdx.x;
  const int wave = tid >> 6, lane = tid & 63;
  const int bid = blockIdx.x;          // 512 = (ystrip2*4 + quarter)*8 + n
  const int n = bid & 7;
  const int rest = bid >> 3;
  const int cob = rest & 3;            // co-quarter
  const int Y0 = (rest >> 2) * 8;      // 16 y-slabs of 8 rows
  const int lo = lane & 15, hi = lane >> 4;

  // quarter weights -> registers once (36 coalesced b128, L2-hot; static idx)
  const short8* wsv = (const short8*)ws_w;
  short8 W[36];                        // [tap*4 + cbl*2 + ks]
  #pragma unroll
  for (int k = 0; k < 36; ++k)
    W[k] = wsv[((k >> 2) * 16 + cob * 4 + (k & 3)) * 64 + lane];

  for (int j = 0; j < 8; ++j) {
    const int ty0 = Y0 + (j >> 2) * 4;       // 2 y-substrips
    const int tx0 = (j & 3) * 32;            // 4 x-subtiles

    // halo DMA: 36 x 1KB chunks (9 per wave), source pre-swizzled
    for (int k = wave; k < 36; k += 4) {
      const int pos = k * 8 + (lane >> 3);
      const int r = pos / 36, c = pos - r * 36;
      const int chunk = (lane & 7) ^ (pos & 7);
      const unsigned short* g =
          ws_x + ((size_t)(n * PH + ty0 + r) * PW + (tx0 + c)) * 64 + chunk * 8;
      g2lds16(g, (char*)halo + k * 1024);
    }
    if (wave < 2) {                          // nb tile (compact plane)
      const float* g = ws_nb
          + (size_t)((n * 128 + ty0 + 2 * wave + (lane >> 5)) * 128)
          + tx0 + (lane & 31);
      g2lds4(g, (char*)nbt + wave * 256);
    }
    __syncthreads();                         // drains vmcnt (DMA complete)

    // acc init from NB (rows=px after operand swap); wave owns row `wave`
    const f32x4 nbv0 = *(const f32x4*)&nbt[wave * 32 + 0  + hi * 4];
    const f32x4 nbv1 = *(const f32x4*)&nbt[wave * 32 + 16 + hi * 4];
    f32x4 acc00 = nbv0, acc01 = nbv1;        // cbl0: h0, h1
    f32x4 acc10 = nbv0, acc11 = nbv1;        // cbl1: h0, h1

    short8 Aaf0, Aaf1;
    short8 Baf0, Baf1;
    short8 Caf0, Caf1;

#define LOADSET(P, K) { \
      constexpr int tap_ = (K) >> 1, ks_ = (K) & 1; \
      constexpr int ty_ = (tap_ / 3) * 2, tx_ = (tap_ % 3) * 2; \
      const int p0_ = (wave + ty_) * 36 + (lo + tx_); \
      const int p1_ = p0_ + 16; \
      P##af0 = halo[p0_ * 8 + ((ks_ * 4 + hi) ^ (p0_ & 7))]; \
      P##af1 = halo[p1_ * 8 + ((ks_ * 4 + hi) ^ (p1_ & 7))]; \
    }
#define MFMASET(P, K) { \
      constexpr int tap_ = (K) >> 1, ks_ = (K) & 1; \
      acc00 = __builtin_amdgcn_mfma_f32_16x16x32_bf16(P##af0, W[tap_ * 4 + 0 + ks_], acc00, 0, 0, 0); \
      acc01 = __builtin_amdgcn_mfma_f32_16x16x32_bf16(P##af1, W[tap_ * 4 + 0 + ks_], acc01, 0, 0, 0); \
      acc10 = __builtin_amdgcn_mfma_f32_16x16x32_bf16(P##af0, W[tap_ * 4 + 2 + ks_], acc10, 0, 0, 0); \
      acc11 = __builtin_amdgcn_mfma_f32_16x16x32_bf16(P##af1, W[tap_ * 4 + 2 + ks_], acc11, 0, 0, 0); \
    }

    LOADSET(A, 0); LOADSET(B, 1);
    LOADSET(C, 2);  MFMASET(A, 0);
    LOADSET(A, 3);  MFMASET(B, 1);
    LOADSET(B, 4);  MFMASET(C, 2);
    LOADSET(C, 5);  MFMASET(A, 3);
    LOADSET(A, 6);  MFMASET(B, 4);
    LOADSET(B, 7);  MFMASET(C, 5);
    LOADSET(C, 8);  MFMASET(A, 6);
    LOADSET(A, 9);  MFMASET(B, 7);
    LOADSET(B, 10); MFMASET(C, 8);
    LOADSET(C, 11); MFMASET(A, 9);
    LOADSET(A, 12); MFMASET(B, 10);
    LOADSET(B, 13); MFMASET(C, 11);
    LOADSET(C, 14); MFMASET(A, 12);
    LOADSET(A, 15); MFMASET(B, 13);
    LOADSET(B, 16); MFMASET(C, 14);
    LOADSET(C, 17); MFMASET(A, 15);
    MFMASET(B, 16);
    MFMASET(C, 17);
#undef LOADSET
#undef MFMASET

    // stores: h0+h1 cover the full 32-px row -> whole 128B lines per block;
    // after the 4 x-subtiles each (co,row) 512B row is fully written.
    {
      const int gy = ty0 + wave;
      const int gx0 = tx0 + hi * 4;
      const int co0 = cob * 32 + lo;
      *(f32x4*)&out[(((size_t)n * CO + co0) * HH + gy) * WW + gx0] = acc00;
      *(f32x4*)&out[(((size_t)n * CO + co0) * HH + gy) * WW + gx0 + 16] = acc01;
      *(f32x4*)&out[(((size_t)n * CO + co0 + 16) * HH + gy) * WW + gx0] = acc10;
      *(f32x4*)&out[(((size_t)n * CO + co0 + 16) * HH + gy) * WW + gx0 + 16] = acc11;
    }
    __syncthreads();                         // protect halo/nbt overwrite
  }
}

// ================= SAFE PATH (Round-2 proven, 705 KB ws) =================
__global__ __launch_bounds__(256) void prep_kernel_safe(
    const float* __restrict__ in, const float* __restrict__ w,
    unsigned short* __restrict__ ws_w, float* __restrict__ ws_T) {
  const int bid = blockIdx.x, tid = threadIdx.x;
  if (bid < 288) {
    const int el = bid * 256 + tid;
    const int tap = el >> 13;
    const int rem = el & 8191;
    const int co = rem >> 6, ic = rem & 63;
    const int ky = (tap / 3) * 2, kx = (tap % 3) * 2;
    ws_w[el] = f2bf(w[(co * 64 + ic) * 25 + ky * 5 + kx]);
  } else {
    const int p = (bid - 288) * 256 + tid;
    const int n = p >> 14;
    const int yx = p & 16383;
    const float* base = in + (size_t)n * CI * (HH * WW) + yx;
    float s = 0.f;
    #pragma unroll
    for (int ic = 0; ic < CI; ++ic) s += base[ic * (HH * WW)];
    ws_T[p] = s;
  }
}

#define SHR 12
#define SHC 36
#define SNPOS (SHR * SHC)

__global__ __launch_bounds__(256, 2) void conv_kernel_safe(
    const float* __restrict__ in, const unsigned short* __restrict__ ws_w,
    const float* __restrict__ ws_T, float* __restrict__ out) {
  __shared__ short8 in_lds[SNPOS * 8];
  __shared__ float T_lds[SNPOS];

  const int tid = threadIdx.x;
  const int t = blockIdx.x;
  const int n = blockIdx.y;
  const int ty0 = (t >> 2) * 8;
  const int tx0 = (t & 3) * 32;

  for (int e = tid; e < SNPOS * 8; e += 256) {
    const int slot = e / SNPOS;
    const int pos = e - slot * SNPOS;
    const int r = pos / SHC, c = pos - r * SHC;
    const int gy = ty0 + r - 2, gx = tx0 + c - 2;
    const bool ok = (gy >= 0 && gy < HH && gx >= 0 && gx < WW);
    const long off = ((long)(n * CI + slot * 8) * HH + gy) * WW + gx;
    short8 pk;
    #pragma unroll
    for (int j = 0; j < 8; ++j) {
      const float v = ok ? in[off + (long)j * (HH * WW)] : 0.f;
      pk[j] = (short)f2bf(v);
    }
    in_lds[pos * 8 + (slot ^ (pos & 7))] = pk;
  }
  for (int e = tid; e < SNPOS; e += 256) {
    const int r = e / SHC, c = e - r * SHC;
    const int gy = ty0 + r - 2, gx = tx0 + c - 2;
    T_lds[e] = (gy >= 0 && gy < HH && gx >= 0 && gx < WW)
                   ? ws_T[((size_t)n * HH + gy) * WW + gx] : 0.f;
  }
  __syncthreads();

  const int wave = tid >> 6;
  const int lane = tid & 63;
  const int lo = lane & 15;
  const int hi = lane >> 4;

  int py[4], pxc[4];
  #pragma unroll
  for (int f = 0; f < 4; ++f) {
    const int pb = wave * 64 + f * 16;
    py[f] = pb >> 5;
    pxc[f] = (pb & 31) + lo;
  }

  f32x4 acc[8][4];
  #pragma unroll
  for (int cb = 0; cb < 8; ++cb)
    #pragma unroll
    for (int f = 0; f < 4; ++f) acc[cb][f] = (f32x4){0.f, 0.f, 0.f, 0.f};

  const short8* wsv = (const short8*)ws_w;

  #pragma unroll
  for (int tap = 0; tap < 9; ++tap) {
    const int ty = (tap / 3) * 2, tx = (tap % 3) * 2;
    #pragma unroll
    for (int ks = 0; ks < 2; ++ks) {
      short8 bfrag[4];
      #pragma unroll
      for (int f = 0; f < 4; ++f) {
        const int pos = (py[f] + ty) * SHC + (pxc[f] + tx);
        bfrag[f] = in_lds[pos * 8 + ((ks * 4 + hi) ^ (pos & 7))];
      }
      #pragma unroll
      for (int cb = 0; cb < 8; ++cb) {
        const short8 afrag = wsv[(tap * 128 + cb * 16 + lo) * 8 + ks * 4 + hi];
        #pragma unroll
        for (int f = 0; f < 4; ++f)
          acc[cb][f] = __builtin_amdgcn_mfma_f32_16x16x32_bf16(
              afrag, bfrag[f], acc[cb][f], 0, 0, 0);
      }
    }
  }

  float nb[4];
  #pragma unroll
  for (int f = 0; f < 4; ++f) {
    float s = 0.f;
    #pragma unroll
    for (int ky = 0; ky < 5; ++ky)
      #pragma unroll
      for (int kx = 0; kx < 5; ++kx)
        if ((ky & 1) | (kx & 1))
          s += T_lds[(py[f] + ky) * SHC + (pxc[f] + kx)];
    nb[f] = s * MU;
  }

  #pragma unroll
  for (int cb = 0; cb < 8; ++cb) {
    #pragma unroll
    for (int f = 0; f < 4; ++f) {
      const int gy = ty0 + py[f];
      const int gx = tx0 + pxc[f];
      #pragma unroll
      for (int q = 0; q < 4; ++q) {
        const int co = cb * 16 + hi * 4 + q;
        out[(((size_t)n * CO + co) * HH + gy) * WW + gx] = acc[cb][f][q] + nb[f];
      }
    }
  }
}

extern "C" void kernel_launch(void* const* d_in, const int* in_sizes, int n_in,
                              void* d_out, int out_size, void* d_ws, size_t ws_size,
                              hipStream_t stream) {
  const float* in = (const float*)d_in[0];
  const float* w  = (const float*)d_in[1];
  float* out = (float*)d_out;
  unsigned short* ws_w = (unsigned short*)d_ws;

  if (ws_size >= WS_TOTAL) {
    float* ws_T = (float*)((char*)d_ws + WS_T_OFF);
    short8* ws_x = (short8*)((char*)d_ws + WS_X_OFF);
    float* ws_nb = (float*)((char*)d_ws + WS_NB_OFF);
    prep_kernel<<<dim3(300), 256, 0, stream>>>(in, w, ws_w, ws_T, ws_x);
    nb_kernel<<<dim3(512), 256, 0, stream>>>(ws_T, ws_nb);
    conv_kernel<<<dim3(512), 256, 0, stream>>>(
        ws_w, ws_nb, (const unsigned short*)ws_x, out);
  } else {
    float* ws_T = (float*)((char*)d_ws + WS_W_BYTES);
    prep_kernel_safe<<<dim3(288 + 512), 256, 0, stream>>>(in, w, ws_w, ws_T);
    conv_kernel_safe<<<dim3(64, NN), 256, 0, stream>>>(in, ws_w, ws_T, out);
  }
}